// Round 1
// 305.455 us; speedup vs baseline: 1.0271x; 1.0271x over previous
//
#include <hip/hip_runtime.h>

// QuaternionLinear as GEMM: M=32768 (batch), N=1024 (OUT_F*4), K=1024 (IN_F*4).
// W_eff[4o+r][4i+c] = sign(r,c) * weight[o][i][r^c], built in d_ws as bf16.
//
// R4: R3's counters (MfmaUtil 27.5%, HBM 25%, VALU 33% — nothing saturated)
// say the 128^2 2-barrier m97 structure is at its documented structural
// ceiling: vmcnt(0)+barrier drains the global_load_lds queue every K-step.
// Fix: port the verified 256^2 8-phase schedule (T3+T4): 512 threads, 8 waves
// (2Mx4N), BK=64, LDS = 2(par) x 2(half) x [128x64] for A and B = 128 KiB,
// one half-tile staged per phase, s_waitcnt vmcnt(4) ONLY at phases 4/8
// (counted, never 0 in-loop), placed before the closing barrier so the
// barrier publishes all waves' completions. Keeps the verified XOR bank
// swizzle (conflict-free), XCD-aware bijective grid swizzle (512 % 8 == 0),
// MFMA fragment mapping and epilogue from R3.

typedef __bf16 bf16x8_t __attribute__((ext_vector_type(8)));
typedef short short8    __attribute__((ext_vector_type(8)));
typedef float f32x4     __attribute__((ext_vector_type(4)));
typedef float f32x8     __attribute__((ext_vector_type(8)));

typedef const unsigned int __attribute__((address_space(1)))* gas_uint_ptr;
typedef unsigned int __attribute__((address_space(3)))*       las_uint_ptr;

// ---------------------------------------------------------------------------
// Prep: build effective bf16 weight matrix W_eff (1024 x 1024), row n = 4o+r,
// col k = 4i+c.  Component select s = r^c; sign bit from table 0x284E.
// ---------------------------------------------------------------------------
__global__ __launch_bounds__(256) void build_weff(const float* __restrict__ w,
                                                  unsigned short* __restrict__ wq) {
    int idx = blockIdx.x * 256 + threadIdx.x;   // 0 .. 1048575
    int n = idx >> 10, k = idx & 1023;
    int o = n >> 2, r = n & 3, i = k >> 2, c = k & 3;
    int s = r ^ c;
    float v = w[o * 1024 + i * 4 + s];
    if ((0x284E >> (r * 4 + c)) & 1) v = -v;
    union { __bf16 b; unsigned short u; } cv;
    cv.b = (__bf16)v;
    wq[idx] = cv.u;
}

// ---------------------------------------------------------------------------
// Streaming fp32 -> bf16 conversion of x (33.5M elements). Pure BW-bound.
// ---------------------------------------------------------------------------
__global__ __launch_bounds__(256) void conv_x(const float* __restrict__ x,
                                              unsigned short* __restrict__ xb) {
    const long long c = (long long)blockIdx.x * 256 + threadIdx.x; // 8-elem chunk
    const float* gp = x + c * 8;
    f32x4 lo = *(const f32x4*)gp;
    f32x4 hi = *(const f32x4*)(gp + 4);
    f32x8 f8 = __builtin_shufflevector(lo, hi, 0, 1, 2, 3, 4, 5, 6, 7);
    bf16x8_t bv = __builtin_convertvector(f8, bf16x8_t);
    union { bf16x8_t b; short8 s; } cv;
    cv.b = bv;
    *(short8*)(xb + c * 8) = cv.s;
}

// ---------------------------------------------------------------------------
// 8-phase 256x256 GEMM. Grid = 512 blocks x 512 threads (8 waves, 2M x 4N).
// Per wave: 128x64 output = acc[8][4] f32x4. BK=64, 2 K-tiles per iteration.
//
// LDS: As/Bs[par][half][128*64] bf16, 16 KiB per half-buffer, 128 KiB total.
// Swizzle: logical 16B chunk g of row r lives at slot g^(r&7); the
// global_load_lds SOURCE address is permuted, destination stays linear.
//
// Per-iteration stage schedule (1 half-tile = 2 global_load_lds / thread):
//   P1: A(2i+1,h0)  P2: A(2i+1,h1)  P3: B(2i+2,h0)  P4: B(2i+2,h1)
//   P5: A(2i+2,h0)  P6: A(2i+2,h1)  P7: B(2i+3,h0)  P8: B(2i+3,h1)
// Buffer-overwrite safety (issue only after last read's closing barrier):
//   As[1] last read P8(prev)  -> staged P1/P2
//   Bs[0] last read P1        -> staged P3/P4
//   As[0] last read P4        -> staged P5/P6
//   Bs[1] last read P5        -> staged P7/P8
// Read-after-load safety: vmcnt(4) at end of P4 (covers A(2i+1),B(2i+1) for
// P5) and end of P8 (covers A(2i+2),B(2i+2) for next P1), BEFORE the closing
// barrier so the barrier publishes every wave's completions. In-flight depth
// oscillates 2..6 half-tiles; vmcnt never drains to 0 in the loop.
// Last iteration clamps kt&15 (stages tile-0 data into dead buffers) so the
// vmcnt counts stay uniform — no branch, no OOB.
// ---------------------------------------------------------------------------
__global__ __launch_bounds__(512, 2) void qlin_gemm_8ph(
        const unsigned short* __restrict__ Xb,
        const unsigned short* __restrict__ Wq,
        const float* __restrict__ bias,
        float* __restrict__ out) {
    __shared__ __align__(16) unsigned short As[2][2][128 * 64];   // 64 KiB
    __shared__ __align__(16) unsigned short Bs[2][2][128 * 64];   // 64 KiB

    const int t    = threadIdx.x;
    const int w    = t >> 6;
    const int l    = t & 63;
    const int lo16 = l & 15;
    const int hi2  = l >> 4;

    const int bid     = blockIdx.x;
    const int xcd     = bid & 7;                 // HW round-robins XCDs
    const int logical = xcd * 64 + (bid >> 3);   // contiguous chunk per XCD
    const int m0      = (logical >> 2) * 256;    // 4 n-tiles share an A panel
    const int n0      = (logical & 3) * 256;

    const int wm  = (w >> 2) * 128;              // 0 / 128
    const int wn  = (w & 3) * 64;                // 0 / 64 / 128 / 192
    const int hA  = wm >> 7;                     // A half read by this wave
    const int hB  = wn >> 7;                     // B half read by this wave
    const int rbB = wn & 64;                     // B row base within half

    f32x4 acc[8][4] = {};
    short8 af[2][2];
    short8 bf[4][2];

    // lane-constant swizzled slot for k-slice ks: (ks*4 + hi2) ^ (lo16 & 7)
    const int sw    = lo16 & 7;
    const int slot0 = hi2 ^ sw;
    const int slot1 = (4 + hi2) ^ sw;

#define STAGE_A(KT, H) do {                                                     \
        const int kk_ = ((KT) & 15) * 64;                                       \
        _Pragma("unroll")                                                       \
        for (int jj = 0; jj < 2; ++jj) {                                        \
            const int idx_ = jj * 512 + t;                                      \
            const int row_ = idx_ >> 3;                                         \
            const int g_   = (idx_ & 7) ^ (row_ & 7);                           \
            const unsigned short* ga_ =                                         \
                Xb + (long long)(m0 + (H) * 128 + row_) * 1024 + kk_ + g_ * 8;  \
            __builtin_amdgcn_global_load_lds((gas_uint_ptr)ga_,                 \
                (las_uint_ptr)(&As[(KT) & 1][(H)][idx_ * 8]), 16, 0, 0);        \
        }                                                                       \
    } while (0)

#define STAGE_B(KT, H) do {                                                     \
        const int kk_ = ((KT) & 15) * 64;                                       \
        _Pragma("unroll")                                                       \
        for (int jj = 0; jj < 2; ++jj) {                                        \
            const int idx_ = jj * 512 + t;                                      \
            const int row_ = idx_ >> 3;                                         \
            const int g_   = (idx_ & 7) ^ (row_ & 7);                           \
            const unsigned short* gb_ =                                         \
                Wq + (n0 + (H) * 128 + row_) * 1024 + kk_ + g_ * 8;             \
            __builtin_amdgcn_global_load_lds((gas_uint_ptr)gb_,                 \
                (las_uint_ptr)(&Bs[(KT) & 1][(H)][idx_ * 8]), 16, 0, 0);        \
        }                                                                       \
    } while (0)

#define READ_BF(PAR) do {                                                       \
        _Pragma("unroll")                                                       \
        for (int nt = 0; nt < 4; ++nt) {                                        \
            const int rl_ = rbB + nt * 16 + lo16;                               \
            bf[nt][0] = *(const short8*)(&Bs[(PAR)][hB][rl_ * 64 + slot0 * 8]); \
            bf[nt][1] = *(const short8*)(&Bs[(PAR)][hB][rl_ * 64 + slot1 * 8]); \
        }                                                                       \
    } while (0)

#define READ_AF(PAR, MTB) do {                                                  \
        _Pragma("unroll")                                                       \
        for (int mi = 0; mi < 2; ++mi) {                                        \
            const int rl_ = ((MTB) + mi) * 16 + lo16;                           \
            af[mi][0] = *(const short8*)(&As[(PAR)][hA][rl_ * 64 + slot0 * 8]); \
            af[mi][1] = *(const short8*)(&As[(PAR)][hA][rl_ * 64 + slot1 * 8]); \
        }                                                                       \
    } while (0)

#define MFMA_Q(MTB) do {                                                        \
        _Pragma("unroll")                                                       \
        for (int mi = 0; mi < 2; ++mi)                                          \
            _Pragma("unroll")                                                   \
            for (int nt = 0; nt < 4; ++nt) {                                    \
                acc[(MTB) + mi][nt] = __builtin_amdgcn_mfma_f32_16x16x32_bf16(  \
                    af[mi][0], bf[nt][0], acc[(MTB) + mi][nt], 0, 0, 0);        \
                acc[(MTB) + mi][nt] = __builtin_amdgcn_mfma_f32_16x16x32_bf16(  \
                    af[mi][1], bf[nt][1], acc[(MTB) + mi][nt], 0, 0, 0);        \
            }                                                                   \
    } while (0)

#define PHASE(PAR, MTB, RDB, ENDW, STAGE_STMT) do {                             \
        if (RDB) READ_BF(PAR);                                                  \
        READ_AF(PAR, MTB);                                                      \
        STAGE_STMT;                                                             \
        asm volatile("s_barrier" ::: "memory");                                 \
        asm volatile("s_waitcnt lgkmcnt(0)" ::: "memory");                      \
        __builtin_amdgcn_s_setprio(1);                                          \
        MFMA_Q(MTB);                                                            \
        __builtin_amdgcn_s_setprio(0);                                          \
        if (ENDW) asm volatile("s_waitcnt vmcnt(4)" ::: "memory");              \
        asm volatile("s_barrier" ::: "memory");                                 \
    } while (0)

    // Prologue: 6 half-tiles in issue order B0,A0,B1; wait the oldest 4
    // (= B0+A0, 8 instr) leaving B1 in flight, then publish via barrier.
    STAGE_B(0, 0); STAGE_B(0, 1);
    STAGE_A(0, 0); STAGE_A(0, 1);
    STAGE_B(1, 0); STAGE_B(1, 1);
    asm volatile("s_waitcnt vmcnt(4)" ::: "memory");
    asm volatile("s_barrier" ::: "memory");

    for (int i = 0; i < 8; ++i) {
        const int kt1 = 2 * i + 1;
        PHASE(0, 0, true,  false, STAGE_A(kt1, 0));      // P1
        PHASE(0, 2, false, false, STAGE_A(kt1, 1));      // P2
        PHASE(0, 4, false, false, STAGE_B(kt1 + 1, 0));  // P3
        PHASE(0, 6, false, true,  STAGE_B(kt1 + 1, 1));  // P4  vmcnt(4)
        PHASE(1, 0, true,  false, STAGE_A(kt1 + 1, 0));  // P5
        PHASE(1, 2, false, false, STAGE_A(kt1 + 1, 1));  // P6
        PHASE(1, 4, false, false, STAGE_B(kt1 + 2, 0));  // P7
        PHASE(1, 6, false, true,  STAGE_B(kt1 + 2, 1));  // P8  vmcnt(4)
    }

#undef STAGE_A
#undef STAGE_B
#undef READ_BF
#undef READ_AF
#undef MFMA_Q
#undef PHASE

    // Epilogue: C/D layout col(n) = lane&15, row(m) = (lane>>4)*4 + reg.
#pragma unroll
    for (int nt = 0; nt < 4; ++nt) {
        const int n  = n0 + wn + nt * 16 + lo16;
        const float bv = bias[n];
#pragma unroll
        for (int mt = 0; mt < 8; ++mt) {
            const int mb = m0 + wm + mt * 16 + hi2 * 4;
#pragma unroll
            for (int r = 0; r < 4; ++r)
                out[(long long)(mb + r) * 1024 + n] = acc[mt][nt][r] + bv;
        }
    }
}

// ---------------------------------------------------------------------------
// Fallback GEMM (R2): fused fp32->bf16 A staging, 128^2 tile. Used only if
// the workspace is too small for the bf16 x copy.
// ---------------------------------------------------------------------------
__global__ __launch_bounds__(256) void qlin_gemm_fused(const float* __restrict__ X,
                                                       const unsigned short* __restrict__ Wq,
                                                       const float* __restrict__ bias,
                                                       float* __restrict__ out) {
    __shared__ __align__(16) unsigned short As[128 * 64];
    __shared__ __align__(16) unsigned short Bs[128 * 64];

    const int t    = threadIdx.x;
    const int w    = t >> 6;
    const int l    = t & 63;
    const int lo16 = l & 15;
    const int hi2  = l >> 4;
    const int bid  = blockIdx.x;
    const int xcd  = bid & 7;
    const int s    = bid >> 3;
    const int m0   = (xcd * 32 + (s >> 3)) * 128;
    const int n0   = (s & 7) * 128;
    const int wm   = (w & 1) * 64;
    const int wn   = (w >> 1) * 64;

    f32x4 acc[4][4] = {};

    for (int kt = 0; kt < 16; ++kt) {
        const int k0 = kt * 64;
        __syncthreads();
#pragma unroll
        for (int jj = 0; jj < 4; ++jj) {
            const int p    = jj * 256 + t;
            const int row  = p >> 3;
            const int g    = (p & 7) ^ (row & 7);
            const unsigned short* gp = Wq + (n0 + row) * 1024 + k0 + g * 8;
            __builtin_amdgcn_global_load_lds((gas_uint_ptr)gp,
                                             (las_uint_ptr)(Bs + p * 8), 16, 0, 0);
        }
#pragma unroll
        for (int jj = 0; jj < 4; ++jj) {
            const int c    = jj * 256 + t;
            const int row  = c >> 3;
            const int g    = c & 7;
            const float* gp = X + (long long)(m0 + row) * 1024 + k0 + g * 8;
            f32x4 lo = *(const f32x4*)gp;
            f32x4 hi = *(const f32x4*)(gp + 4);
            f32x8 f8 = __builtin_shufflevector(lo, hi, 0, 1, 2, 3, 4, 5, 6, 7);
            bf16x8_t bv = __builtin_convertvector(f8, bf16x8_t);
            union { bf16x8_t b; short8 s; } cv;
            cv.b = bv;
            const int p = row * 8 + (g ^ (row & 7));
            *(short8*)(As + p * 8) = cv.s;
        }
        __syncthreads();
#pragma unroll
        for (int ks = 0; ks < 2; ++ks) {
            const int g = ks * 4 + hi2;
            short8 af[4], bf[4];
#pragma unroll
            for (int mt = 0; mt < 4; ++mt) {
                const int r = wm + mt * 16 + lo16;
                af[mt] = *(const short8*)(As + (r * 8 + (g ^ (r & 7))) * 8);
            }
#pragma unroll
            for (int nt = 0; nt < 4; ++nt) {
                const int r = wn + nt * 16 + lo16;
                bf[nt] = *(const short8*)(Bs + (r * 8 + (g ^ (r & 7))) * 8);
            }
#pragma unroll
            for (int mt = 0; mt < 4; ++mt)
#pragma unroll
                for (int nt = 0; nt < 4; ++nt)
                    acc[mt][nt] = __builtin_amdgcn_mfma_f32_16x16x32_bf16(
                        af[mt], bf[nt], acc[mt][nt], 0, 0, 0);
        }
    }

#pragma unroll
    for (int nt = 0; nt < 4; ++nt) {
        const int n  = n0 + wn + nt * 16 + lo16;
        const float bv = bias[n];
#pragma unroll
        for (int mt = 0; mt < 4; ++mt) {
            const int mb = m0 + wm + mt * 16 + hi2 * 4;
#pragma unroll
            for (int r = 0; r < 4; ++r)
                out[(long long)(mb + r) * 1024 + n] = acc[mt][nt][r] + bv;
        }
    }
}

// ---------------------------------------------------------------------------
extern "C" void kernel_launch(void* const* d_in, const int* in_sizes, int n_in,
                              void* d_out, int out_size, void* d_ws, size_t ws_size,
                              hipStream_t stream) {
    const float* x  = (const float*)d_in[0];   // (32768, 256, 4) fp32
    const float* wt = (const float*)d_in[1];   // (256, 256, 4) fp32
    const float* bs = (const float*)d_in[2];   // (256, 4) fp32
    float* out = (float*)d_out;                // (32768, 256, 4) fp32

    unsigned short* wq = (unsigned short*)d_ws;            // 2 MiB W_eff bf16
    const size_t WQ_BYTES = 1024ull * 1024 * 2;
    const size_t XB_BYTES = 32768ull * 1024 * 2;           // 64 MiB x bf16

    build_weff<<<4096, 256, 0, stream>>>(wt, wq);

    if (ws_size >= WQ_BYTES + XB_BYTES) {
        unsigned short* xb = (unsigned short*)((char*)d_ws + WQ_BYTES);
        conv_x<<<16384, 256, 0, stream>>>(x, xb);          // 33.5M elems / 8
        qlin_gemm_8ph<<<512, 512, 0, stream>>>(xb, wq, bs, out);
    } else {
        qlin_gemm_fused<<<2048, 256, 0, stream>>>(x, wq, bs, out);
    }

    (void)in_sizes; (void)n_in; (void)out_size;
}